// Round 10
// baseline (164.843 us; speedup 1.0000x reference)
//
#include <hip/hip_runtime.h>
#include <hip/hip_bf16.h>
#include <math.h>

#define B_DIM 4
#define C_DIM 256
#define CQK_DIM 32
#define N_POS 4096
#define NPART 4          // j-split partitions (16 tiles each)

typedef unsigned short u16;
typedef __attribute__((ext_vector_type(8))) short bf16x8;
typedef __attribute__((ext_vector_type(4))) float f32x4;

__device__ __forceinline__ u16 f32_to_bf16_rn(float f) {
    union { float f; unsigned int u; } v; v.f = f;
    unsigned int u = v.u;
    u += 0x7fffu + ((u >> 16) & 1u);
    return (u16)(u >> 16);
}
__device__ __forceinline__ float bf16_to_f32(u16 h) {
    union { unsigned int u; float f; } v; v.u = ((unsigned int)h) << 16;
    return v.f;
}
__device__ __forceinline__ void async_copy16(const u16* g, u16* l) {
    __builtin_amdgcn_global_load_lds(
        (const __attribute__((address_space(1))) void*)g,
        (__attribute__((address_space(3))) void*)l, 16, 0, 0);
}

// ---------------------------------------------------------------------------
// FRAGMENT-ORDER LAYOUTS (proven R8/R9): operand fragment = 64 lanes x 8 bf16.
//  V B-frag (cb,kb): lane l,e -> V[c=cb*16+(l&15)][j=kb*32+(l>>4)*8+e],
//    frag_id=cb*2+kb (32 frags = 32 KB / 64-j tile)
//  K B-frag (jb): lane l,e -> K[j=jb*16+(l&15)][cqk=(l>>4)*8+e], frag_id=jb
//  P A-frag (m):  lane l,e -> P[i=m*16+(l&15)][j=kb*32+(l>>4)*8+e] (kb-split)
// ---------------------------------------------------------------------------

// ---------------------------------------------------------------------------
// Projection, round 10. R9's proj built B-frags with 8 stride-16KB global
// dwords per frag (256 loads -> ~1024 L1 line txns per wave, latency-bound at
// 4 waves/CU). Now: stage x-tile TRANSPOSED in LDS (xs[64 n][260 c] fp32,
// 66.5 KB; pad 260 -> 16B-aligned rows, uniform bank spread), so each B-frag
// is 2 ds_read_b128 (lane-contiguous). Global x reads: one coalesced 64 KB
// tile copy. W/A-frags, MFMA structure, V/K/q stores identical to R9.
// ---------------------------------------------------------------------------
__global__ __launch_bounds__(256) void proj_kernel(
    const float* __restrict__ x,
    const float* __restrict__ Wq, const float* __restrict__ bq,
    const float* __restrict__ Wk, const float* __restrict__ bk,
    const float* __restrict__ Wv, const float* __restrict__ bv,
    u16* __restrict__ qhi, u16* __restrict__ qlo,
    u16* __restrict__ kth, u16* __restrict__ ktl,
    u16* __restrict__ vtile)
{
    __shared__ float xs[64][260];       // 66,560 B (transposed x tile)

    const int t    = threadIdx.x;
    const int blk  = blockIdx.x;        // 0..255 = (b, jt)
    const int b    = blk >> 6;
    const int jt   = blk & 63;
    const int n0   = jt * 64;
    const int wave = t >> 6;
    const int lane = t & 63;
    const int n16  = lane & 15;
    const int quad = lane >> 4;
    const float* xb = x + (size_t)b * C_DIM * N_POS;

    // stage + transpose: threads (c, n4): coalesced float4 read along n,
    // scatter 4 b32 LDS writes (bank cost minor, ~0.4us/block)
    for (int f = t; f < C_DIM * 16; f += 256) {
        const int c = f >> 4, n4 = f & 15;
        float4 v = *(const float4*)(xb + (size_t)c * N_POS + n0 + n4 * 4);
        xs[n4 * 4 + 0][c] = v.x;
        xs[n4 * 4 + 1][c] = v.y;
        xs[n4 * 4 + 2][c] = v.z;
        xs[n4 * 4 + 3][c] = v.w;
    }
    __syncthreads();

    f32x4 accV[4][4];
    f32x4 accQ[4];
    #pragma unroll
    for (int v = 0; v < 4; ++v)
        #pragma unroll
        for (int nt = 0; nt < 4; ++nt) accV[v][nt] = (f32x4){0.f,0.f,0.f,0.f};
    #pragma unroll
    for (int nt = 0; nt < 4; ++nt) accQ[nt] = (f32x4){0.f,0.f,0.f,0.f};

    const float* Wqk  = (wave < 2) ? Wq : Wk;
    const int    qkrow = (wave & 1) * 16 + n16;

    for (int kk = 0; kk < 8; ++kk) {
        const int k0 = kk * 32 + quad * 8;
        // ---- B-frags from LDS: xs[nt*16+n16][k0 .. k0+8], 2 b128 each
        bf16x8 bh[4], bl[4];
        #pragma unroll
        for (int nt = 0; nt < 4; ++nt) {
            const float* xp = &xs[nt * 16 + n16][k0];
            float xv[8];
            #pragma unroll
            for (int j = 0; j < 8; ++j) xv[j] = xp[j];
            #pragma unroll
            for (int j = 0; j < 8; ++j) {
                u16 h = f32_to_bf16_rn(xv[j]);
                bh[nt][j] = (short)h;
                bl[nt][j] = (short)f32_to_bf16_rn(xv[j] - bf16_to_f32(h));
            }
        }
        // ---- V: A-frags (global W, L2-hot) + MFMA
        #pragma unroll
        for (int v = 0; v < 4; ++v) {
            const float* wr = Wv + (size_t)(wave * 64 + v * 16 + n16) * C_DIM + k0;
            float4 a0 = *(const float4*)(wr);
            float4 a1 = *(const float4*)(wr + 4);
            bf16x8 ah;
            ah[0] = (short)f32_to_bf16_rn(a0.x); ah[1] = (short)f32_to_bf16_rn(a0.y);
            ah[2] = (short)f32_to_bf16_rn(a0.z); ah[3] = (short)f32_to_bf16_rn(a0.w);
            ah[4] = (short)f32_to_bf16_rn(a1.x); ah[5] = (short)f32_to_bf16_rn(a1.y);
            ah[6] = (short)f32_to_bf16_rn(a1.z); ah[7] = (short)f32_to_bf16_rn(a1.w);
            #pragma unroll
            for (int nt = 0; nt < 4; ++nt)
                accV[v][nt] = __builtin_amdgcn_mfma_f32_16x16x32_bf16(
                    ah, bh[nt], accV[v][nt], 0, 0, 0);
        }
        // ---- q/k: A-frag hi+lo, 3-pass MFMA (fp32-accurate)
        {
            const float* wr = Wqk + (size_t)qkrow * C_DIM + k0;
            bf16x8 ah, al;
            #pragma unroll
            for (int j = 0; j < 8; ++j) {
                float w = wr[j];
                u16 h = f32_to_bf16_rn(w);
                ah[j] = (short)h;
                al[j] = (short)f32_to_bf16_rn(w - bf16_to_f32(h));
            }
            #pragma unroll
            for (int nt = 0; nt < 4; ++nt) {
                accQ[nt] = __builtin_amdgcn_mfma_f32_16x16x32_bf16(ah, bh[nt], accQ[nt], 0, 0, 0);
                accQ[nt] = __builtin_amdgcn_mfma_f32_16x16x32_bf16(ah, bl[nt], accQ[nt], 0, 0, 0);
                accQ[nt] = __builtin_amdgcn_mfma_f32_16x16x32_bf16(al, bh[nt], accQ[nt], 0, 0, 0);
            }
        }
    }

    // ---- V stores, fragment order (identical to R9)
    u16* vt = vtile + (size_t)(b * 64 + jt) * (32 * 512);
    #pragma unroll
    for (int v = 0; v < 4; ++v) {
        const int cb = wave * 4 + v;
        #pragma unroll
        for (int r = 0; r < 4; ++r) {
            const int c = cb * 16 + quad * 4 + r;
            const float bias = bv[c];
            #pragma unroll
            for (int nt = 0; nt < 4; ++nt) {
                const int kb = nt >> 1;
                const int qd = (nt & 1) * 2 + (n16 >> 3);
                vt[(cb * 2 + kb) * 512 + (qd * 16 + quad * 4 + r) * 8 + (n16 & 7)] =
                    f32_to_bf16_rn(accV[v][nt][r] + bias);
            }
        }
    }
    if (wave < 2) {
        #pragma unroll
        for (int r = 0; r < 4; ++r) {
            const int c = (wave & 1) * 16 + quad * 4 + r;
            const float bias = bq[c];
            #pragma unroll
            for (int nt = 0; nt < 4; ++nt) {
                float val = accQ[nt][r] + bias;
                u16 h = f32_to_bf16_rn(val);
                u16 lo = f32_to_bf16_rn(val - bf16_to_f32(h));
                size_t base = ((size_t)b * N_POS + n0 + nt * 16 + n16) * CQK_DIM + c;
                qhi[base] = h; qlo[base] = lo;
            }
        }
    } else {
        u16* kh_t = kth + (size_t)(b * 64 + jt) * (4 * 512);
        u16* kl_t = ktl + (size_t)(b * 64 + jt) * (4 * 512);
        #pragma unroll
        for (int r = 0; r < 4; ++r) {
            const int c = (wave & 1) * 16 + quad * 4 + r;
            const float bias = bk[c];
            #pragma unroll
            for (int nt = 0; nt < 4; ++nt) {
                float val = accQ[nt][r] + bias;
                u16 h = f32_to_bf16_rn(val);
                u16 lo = f32_to_bf16_rn(val - bf16_to_f32(h));
                const int off = nt * 512 + ((c >> 3) * 16 + n16) * 8 + (c & 7);
                kh_t[off] = h; kl_t[off] = lo;
            }
        }
    }
}

// ---------------------------------------------------------------------------
// Flash attention — FROZEN from R9 (measured 59.5us): independent waves,
// fragment-order layouts, 32 i-rows/wave, double-buffered Vt, 1 barrier/tile.
// ---------------------------------------------------------------------------
__global__ __launch_bounds__(256, 2) void flash_kernel(
    const u16* __restrict__ qhi, const u16* __restrict__ qlo,
    const u16* __restrict__ kth, const u16* __restrict__ ktl,
    const u16* __restrict__ vtile,
    u16* __restrict__ part, float2* __restrict__ ml)
{
    __shared__ u16 Vt[2][32 * 512];   // 64 KB double-buffered V tile
    __shared__ u16 pbuf[4][2 * 512];  // per-wave P half-tile (kb-split), 8 KB

    const int t    = threadIdx.x;
    const int wave = t >> 6;
    const int lane = t & 63;
    const int n16  = lane & 15;
    const int quad = lane >> 4;

    const int idx    = blockIdx.x;          // 0..511
    const int xcd    = idx & 7;
    const int b      = xcd & 3;
    const int z      = idx >> 3;            // 0..63
    const int p      = z & 3;
    const int iouter = z >> 2;              // 0..15
    const int itile  = (iouter << 1) | (xcd >> 2);   // 0..31
    const int i0     = itile * 128 + wave * 32;      // wave's 32 rows

    bf16x8 qh[2], ql[2];
    #pragma unroll
    for (int m = 0; m < 2; ++m) {
        qh[m] = *(const bf16x8*)(qhi + ((size_t)b * N_POS + i0 + m * 16 + n16) * CQK_DIM + quad * 8);
        ql[m] = *(const bf16x8*)(qlo + ((size_t)b * N_POS + i0 + m * 16 + n16) * CQK_DIM + quad * 8);
    }

    f32x4 O[2][16];
    #pragma unroll
    for (int m = 0; m < 2; ++m)
        #pragma unroll
        for (int cb = 0; cb < 16; ++cb) O[m][cb] = (f32x4){0.f, 0.f, 0.f, 0.f};
    float lsum[2][4] = {{0.f,0.f,0.f,0.f},{0.f,0.f,0.f,0.f}};

    u16* pb = pbuf[wave];
    const int jt_beg = p * 16;
    const int jt_end = jt_beg + 16;

    {
        const u16* vsrc = vtile + (size_t)(b * 64 + jt_beg) * (32 * 512);
        for (int ch = wave; ch < 32; ch += 4)
            async_copy16(vsrc + ch * 512 + lane * 8, Vt[0] + ch * 512);
    }

    int buf = 0;
    for (int jt = jt_beg; jt < jt_end; ++jt) {
        const u16* kh_t = kth + (size_t)(b * 64 + jt) * (4 * 512);
        const u16* kl_t = ktl + (size_t)(b * 64 + jt) * (4 * 512);
        bf16x8 kh[4], kl[4];
        #pragma unroll
        for (int jb = 0; jb < 4; ++jb) {
            kh[jb] = *(const bf16x8*)(kh_t + jb * 512 + lane * 8);
            kl[jb] = *(const bf16x8*)(kl_t + jb * 512 + lane * 8);
        }
        __syncthreads();   // drains V DMA into Vt[buf] (+K); 1 barrier/tile

        if (jt + 1 < jt_end) {
            const u16* vsrc = vtile + (size_t)(b * 64 + jt + 1) * (32 * 512);
            for (int ch = wave; ch < 32; ch += 4)
                async_copy16(vsrc + ch * 512 + lane * 8, Vt[buf ^ 1] + ch * 512);
        }

        f32x4 s[2][4];
        #pragma unroll
        for (int m = 0; m < 2; ++m)
            #pragma unroll
            for (int jb = 0; jb < 4; ++jb) {
                f32x4 acc = (f32x4){0.f, 0.f, 0.f, 0.f};
                acc = __builtin_amdgcn_mfma_f32_16x16x32_bf16(qh[m], kh[jb], acc, 0, 0, 0);
                acc = __builtin_amdgcn_mfma_f32_16x16x32_bf16(qh[m], kl[jb], acc, 0, 0, 0);
                acc = __builtin_amdgcn_mfma_f32_16x16x32_bf16(ql[m], kh[jb], acc, 0, 0, 0);
                s[m][jb] = acc;
            }
        #pragma unroll
        for (int m = 0; m < 2; ++m)
            #pragma unroll
            for (int jb = 0; jb < 4; ++jb)
                #pragma unroll
                for (int r = 0; r < 4; ++r) {
                    float pv = __expf(s[m][jb][r]);
                    s[m][jb][r] = pv;
                    lsum[m][r] += pv;
                }

        const u16* vb = Vt[buf];
        #pragma unroll
        for (int kb = 0; kb < 2; ++kb) {
            #pragma unroll
            for (int m = 0; m < 2; ++m)
                #pragma unroll
                for (int j2 = 0; j2 < 2; ++j2) {
                    const int jb = kb * 2 + j2;
                    const int fr = m * 512 +
                        ((j2 * 2 + (n16 >> 3)) * 16 + quad * 4) * 8 + (n16 & 7);
                    #pragma unroll
                    for (int r = 0; r < 4; ++r)
                        pb[fr + r * 8] = f32_to_bf16_rn(s[m][jb][r]);
                }
            asm volatile("s_waitcnt lgkmcnt(0)" ::: "memory");
            bf16x8 Pf[2];
            #pragma unroll
            for (int m = 0; m < 2; ++m)
                Pf[m] = *(const bf16x8*)(pb + m * 512 + lane * 8);
            #pragma unroll
            for (int cb = 0; cb < 16; ++cb) {
                bf16x8 Vf = *(const bf16x8*)(vb + (cb * 2 + kb) * 512 + lane * 8);
                #pragma unroll
                for (int m = 0; m < 2; ++m)
                    O[m][cb] = __builtin_amdgcn_mfma_f32_16x16x32_bf16(
                        Pf[m], Vf, O[m][cb], 0, 0, 0);
            }
        }
        buf ^= 1;
    }

    #pragma unroll
    for (int off = 1; off <= 8; off <<= 1)
        #pragma unroll
        for (int m = 0; m < 2; ++m)
            #pragma unroll
            for (int r = 0; r < 4; ++r)
                lsum[m][r] += __shfl_xor(lsum[m][r], off, 64);
    float inv_l[2][4];
    #pragma unroll
    for (int m = 0; m < 2; ++m)
        #pragma unroll
        for (int r = 0; r < 4; ++r) inv_l[m][r] = 1.f / lsum[m][r];

    u16* pbase = part + ((size_t)(p * 4 + b) * N_POS + i0) * C_DIM;
    #pragma unroll
    for (int m = 0; m < 2; ++m)
        #pragma unroll
        for (int cb = 0; cb < 16; ++cb)
            #pragma unroll
            for (int r = 0; r < 4; ++r)
                pbase[(size_t)(m * 16 + quad * 4 + r) * C_DIM + cb * 16 + n16] =
                    f32_to_bf16_rn(O[m][cb][r] * inv_l[m][r]);
    if (n16 == 0) {
        #pragma unroll
        for (int m = 0; m < 2; ++m)
            #pragma unroll
            for (int r = 0; r < 4; ++r)
                ml[(size_t)(p * 4 + b) * N_POS + i0 + m * 16 + quad * 4 + r] =
                    make_float2(0.f, lsum[m][r]);
    }
}

// ---------------------------------------------------------------------------
// Reduce — FROZEN from R9 (NPART=4 combine + transpose + residual).
// ---------------------------------------------------------------------------
__global__ __launch_bounds__(256) void reduce_kernel(
    const u16* __restrict__ part, const float2* __restrict__ ml,
    const float* __restrict__ x, float* __restrict__ out)
{
    const int TJ = 32;
    __shared__ float wgt[NPART][TJ];
    __shared__ float trans[C_DIM][TJ + 1];

    const int t   = threadIdx.x;
    const int blk = blockIdx.x;      // 0..511
    const int b   = blk >> 7;
    const int n0  = (blk & 127) * TJ;

    if (t < TJ) {
        int i = n0 + t;
        float s = 0.f, w[NPART];
        #pragma unroll
        for (int p = 0; p < NPART; ++p) {
            float2 a = ml[(size_t)(p * 4 + b) * N_POS + i];
            w[p] = a.y;          // m == 0 for all partitions
            s += w[p];
        }
        float inv = 1.f / s;
        #pragma unroll
        for (int p = 0; p < NPART; ++p) wgt[p][t] = w[p] * inv;
    }
    __syncthreads();

    {
        const int cp = t & 127;
        const int ih = t >> 7;
        for (int ib = 0; ib < TJ; ib += 2) {
            int i = ib + ih;
            float acc0 = 0.f, acc1 = 0.f;
            #pragma unroll
            for (int p = 0; p < NPART; ++p) {
                const u16* row = part + ((size_t)(p * 4 + b) * N_POS + n0 + i) * C_DIM;
                ushort2 pv = ((const ushort2*)row)[cp];
                float wp = wgt[p][i];
                acc0 += wp * bf16_to_f32(pv.x);
                acc1 += wp * bf16_to_f32(pv.y);
            }
            trans[2 * cp][i]     = acc0;
            trans[2 * cp + 1][i] = acc1;
        }
    }
    __syncthreads();

    {
        const int il = t & 31;
        const int cr = t >> 5;
        const float* xb = x + (size_t)b * C_DIM * N_POS;
        float* ob       = out + (size_t)b * C_DIM * N_POS;
        for (int cc = 0; cc < 32; ++cc) {
            int c = cc * 8 + cr;
            size_t g = (size_t)c * N_POS + n0 + il;
            ob[g] = trans[c][il] + xb[g];
        }
    }
}

extern "C" void kernel_launch(void* const* d_in, const int* in_sizes, int n_in,
                              void* d_out, int out_size, void* d_ws, size_t ws_size,
                              hipStream_t stream) {
    const float* x  = (const float*)d_in[0];
    const float* Wq = (const float*)d_in[1];
    const float* bq = (const float*)d_in[2];
    const float* Wk = (const float*)d_in[3];
    const float* bk = (const float*)d_in[4];
    const float* Wv = (const float*)d_in[5];
    const float* bv = (const float*)d_in[6];
    float* out = (float*)d_out;

    // ws layout (44.5 MiB == R1-proven bound):
    //   0 MiB  qhi (1)   1 MiB  qlo (1)
    //   2 MiB  kth [B,64,4,512] u16 (1)   3 MiB  ktl (1)
    //   4 MiB  vtile [B,64,32,512] u16 (8)
    //  12 MiB  part [4,B,N,C] bf16 (32)
    //  44 MiB  ml [4,B,N] float2 (0.5)
    char* ws = (char*)d_ws;
    u16*    qhi   = (u16*)(ws);
    u16*    qlo   = (u16*)(ws + (1ull << 20));
    u16*    kth   = (u16*)(ws + (2ull << 20));
    u16*    ktl   = (u16*)(ws + (3ull << 20));
    u16*    vtile = (u16*)(ws + (4ull << 20));
    u16*    part  = (u16*)(ws + (12ull << 20));
    float2* mlp   = (float2*)(ws + (44ull << 20));

    hipLaunchKernelGGL(proj_kernel, dim3(256), dim3(256), 0, stream,
                       x, Wq, bq, Wk, bk, Wv, bv, qhi, qlo, kth, ktl, vtile);
    hipLaunchKernelGGL(flash_kernel, dim3(512), dim3(256), 0, stream,
                       qhi, qlo, kth, ktl, vtile, part, mlp);
    hipLaunchKernelGGL(reduce_kernel, dim3(512), dim3(256), 0, stream,
                       part, mlp, x, out);
}